// Round 2
// baseline (626.180 us; speedup 1.0000x reference)
//
#include <hip/hip_runtime.h>

// DEC soft assignment: q = rownorm(1/(1 + ||x-c||^2)), ALPHA=1 so power term is identity.
// bf16 MFMA for x.c^T (error budget: dq ~ 2e-7 << 4e-5 threshold); fp32 x^2/c^2/normalize.
// R2: MT 64, wave tile 64x128, B staged via global_load_lds w/ XOR-chunk swizzle. (214 us)
// R3: B-from-L2 scatter reads -- REGRESSED (242 us): 16 cacheline-txns per B load saturated
//     TA pipe; LDA=520 caused 4-way A bank conflicts. Reverted.
// R4: keep R2 layouts (APAD=36, B chunk-swizzle) but remove the per-step vmcnt(0) drain:
//     - double-buffer A (9KB) and B (64KB) in LDS; 76.3KB total -> still 2 blocks/CU
//     - raw __builtin_amdgcn_s_barrier() + manual lgkmcnt(0); NO vmcnt drain in-loop.
//       B(kt+1) gload_lds stay in flight across the barrier + MFMA phase (T3/T4).
//     - B(kt) completion is guaranteed by the compiler's own vmcnt wait for the x-register
//       prefetch consumed at the top of iter kt (x loads issued AFTER B(kt); order pinned
//       with sched_barrier(0)). kt==15 gets an explicit vmcnt(0).
//     - barrier 2 placed right after frag ds_reads (lgkmcnt(0)) so next-iter staging
//       overlaps this iter's MFMAs.

typedef __attribute__((ext_vector_type(8))) short short8_t;
typedef __attribute__((ext_vector_type(4))) short short4_t;
typedef __attribute__((ext_vector_type(4))) float f32x4;

#define NROWS 131072
#define DDIM  512
#define NCL   512
#define BK    32
#define MT    64
#define APAD  36   // A row stride in shorts: 72B = 16 distinct 16B-slot starts, 2-way-free b128

__device__ __forceinline__ unsigned short f2bf(float f) {
    unsigned u = __float_as_uint(f);
    u += 0x7FFFu + ((u >> 16) & 1u);
    return (unsigned short)(u >> 16);
}

// ---- prep: convert centers to bf16, compute ||c_k||^2 in fp32 ----
__global__ __launch_bounds__(128) void prep_centers(
        const float* __restrict__ c, unsigned short* __restrict__ cb,
        float* __restrict__ c2) {
    const int k = blockIdx.x, t = threadIdx.x;
    float4 v = ((const float4*)(c + k * DDIM))[t];
    float ss = v.x * v.x + v.y * v.y + v.z * v.z + v.w * v.w;
    short4_t s;
    s.x = (short)f2bf(v.x); s.y = (short)f2bf(v.y);
    s.z = (short)f2bf(v.z); s.w = (short)f2bf(v.w);
    ((short4_t*)(cb + k * DDIM))[t] = s;
#pragma unroll
    for (int off = 32; off >= 1; off >>= 1) ss += __shfl_xor(ss, off, 64);
    __shared__ float red[2];
    if ((t & 63) == 0) red[t >> 6] = ss;
    __syncthreads();
    if (t == 0) c2[k] = red[0] + red[1];
}

// ---- main: 64 rows x 512 clusters per block, 256 threads = 4 waves (each 64x128) ----
__global__ __launch_bounds__(256, 2) void dec_soft_assign(
        const float* __restrict__ x, const unsigned short* __restrict__ cb,
        const float* __restrict__ c2g, float* __restrict__ out) {
    __shared__ __align__(16) unsigned short Alds[2][MT * APAD];   // 2 x 4.5 KB
    __shared__ __align__(16) unsigned short Blds[2][NCL * BK];    // 2 x 32 KB, XOR-chunk swizzled
    __shared__ float x2_lds[MT];
    __shared__ float rs_lds[MT][4];
    __shared__ float inv_lds[MT];

    const int t   = threadIdx.x;
    const int w   = t >> 6;        // wave 0..3
    const int l   = t & 63;
    const int q   = l >> 4;        // quad
    const int l15 = l & 15;
    const int m0  = blockIdx.x * MT;

    // A staging: thread t owns row ar, 8-elem k-chunk acj per step
    const int ar  = t >> 2;        // 0..63
    const int acj = t & 3;         // 0..3
    const float4* xp = (const float4*)(x + (long)(m0 + ar) * DDIM) + acj * 2;

    // B staging: 512 cols x 4 chunks(16B) = 2048 chunks; chunk cl = i*256 + t.
    // Physical slot (n, cp) holds global k-chunk cc = cp ^ ((n>>1)&3)  (bank swizzle).
    int bgo[8];
#pragma unroll
    for (int i = 0; i < 8; ++i) {
        int cl = i * 256 + t;
        int n  = cl >> 2;
        int cp = cl & 3;
        int cc = cp ^ ((n >> 1) & 3);
        bgo[i] = n * DDIM + cc * 8;          // short index (add kt*BK per step)
    }

    f32x4 acc[4][8];
#pragma unroll
    for (int mt = 0; mt < 4; ++mt)
#pragma unroll
        for (int nt = 0; nt < 8; ++nt)
            acc[mt][nt] = (f32x4){0.f, 0.f, 0.f, 0.f};

    float x2a = 0.f;
    float4 v0, v1;

#define STAGE_A(buf) do {                                                    \
        x2a += v0.x * v0.x + v0.y * v0.y + v0.z * v0.z + v0.w * v0.w;        \
        x2a += v1.x * v1.x + v1.y * v1.y + v1.z * v1.z + v1.w * v1.w;        \
        short8_t a8;                                                         \
        a8[0] = (short)f2bf(v0.x); a8[1] = (short)f2bf(v0.y);                \
        a8[2] = (short)f2bf(v0.z); a8[3] = (short)f2bf(v0.w);                \
        a8[4] = (short)f2bf(v1.x); a8[5] = (short)f2bf(v1.y);                \
        a8[6] = (short)f2bf(v1.z); a8[7] = (short)f2bf(v1.w);                \
        *(short8_t*)&Alds[buf][ar * APAD + acj * 8] = a8;                    \
    } while (0)

#define ISSUE_B(buf, ktc) do {                                               \
        _Pragma("unroll")                                                    \
        for (int i = 0; i < 8; ++i)                                          \
            __builtin_amdgcn_global_load_lds(                                \
                (const __attribute__((address_space(1))) void*)(cb + bgo[i] + (ktc) * BK), \
                (__attribute__((address_space(3))) void*)&Blds[buf][(i * 256 + w * 64) * 8], \
                16, 0, 0);                                                   \
    } while (0)

    // ---- prologue: stage chunk 0, issue B(0), prefetch x chunk 1 ----
    v0 = xp[0]; v1 = xp[1];
    STAGE_A(0);
    ISSUE_B(0, 0);
    __builtin_amdgcn_sched_barrier(0);
    v0 = xp[8]; v1 = xp[9];                  // chunk 1 (issued AFTER B(0): its consumption
    __builtin_amdgcn_sched_barrier(0);       //  at iter 0 drains B(0) for free)

#pragma unroll
    for (int kt = 0; kt < 16; ++kt) {
        const int cur = kt & 1, nxt = cur ^ 1;
        if (kt < 15) {
            // stage A(kt+1): the v0/v1 use here forces the compiler's vmcnt wait,
            // which (order pinned) also covers B(kt) issued last iteration.
            STAGE_A(nxt);
            ISSUE_B(nxt, kt + 1);
            __builtin_amdgcn_sched_barrier(0);
            if (kt < 14) { v0 = xp[(kt + 2) * 8]; v1 = xp[(kt + 2) * 8 + 1]; }
            __builtin_amdgcn_sched_barrier(0);
        }
        asm volatile("s_waitcnt lgkmcnt(0)" ::: "memory");   // A writes visible
        if (kt == 15) asm volatile("s_waitcnt vmcnt(0)" ::: "memory"); // B(15) landed
        __builtin_amdgcn_sched_barrier(0);
        __builtin_amdgcn_s_barrier();                        // bar1: buf[cur] ready
        __builtin_amdgcn_sched_barrier(0);

        // ---- frag reads from buf[cur] ----
        short8_t afr[4], bfr[8];
#pragma unroll
        for (int mt = 0; mt < 4; ++mt)
            afr[mt] = *(const short8_t*)&Alds[cur][(mt * 16 + l15) * APAD + q * 8];
#pragma unroll
        for (int nt = 0; nt < 8; ++nt) {
            int n  = w * 128 + nt * 16 + l15;
            int pc = q ^ ((n >> 1) & 3);
            bfr[nt] = *(const short8_t*)&Blds[cur][n * BK + pc * 8];
        }
        asm volatile("s_waitcnt lgkmcnt(0)" ::: "memory");   // frags in regs
        __builtin_amdgcn_sched_barrier(0);
        if (kt < 15) __builtin_amdgcn_s_barrier();           // bar2: release buf[cur]
        __builtin_amdgcn_sched_barrier(0);

        // ---- MFMA phase: overlaps next iter's staging in other waves ----
#pragma unroll
        for (int nt = 0; nt < 8; ++nt)
#pragma unroll
            for (int mt = 0; mt < 4; ++mt)
                acc[mt][nt] = __builtin_amdgcn_mfma_f32_16x16x32_bf16(afr[mt], bfr[nt], acc[mt][nt], 0, 0, 0);
    }

    // ---- x^2 per row: reduce the 4 staging lanes of each row ----
    x2a += __shfl_xor(x2a, 1, 64);
    x2a += __shfl_xor(x2a, 2, 64);
    if (acj == 0) x2_lds[ar] = x2a;
    __syncthreads();

    // ---- epilogue: dist2 -> clamp -> 1/(1+d), row sums ----
    float c2v[8];
#pragma unroll
    for (int nt = 0; nt < 8; ++nt)
        c2v[nt] = c2g[w * 128 + nt * 16 + l15];

    float rsum[4][4];
#pragma unroll
    for (int mt = 0; mt < 4; ++mt)
#pragma unroll
        for (int r = 0; r < 4; ++r) rsum[mt][r] = 0.f;

#pragma unroll
    for (int mt = 0; mt < 4; ++mt) {
#pragma unroll
        for (int r = 0; r < 4; ++r) {
            float xv = x2_lds[mt * 16 + q * 4 + r];
#pragma unroll
            for (int nt = 0; nt < 8; ++nt) {
                float d = xv + c2v[nt] - 2.0f * acc[mt][nt][r];
                d = fmaxf(d, 0.0f);
                float qq = __builtin_amdgcn_rcpf(1.0f + d);
                acc[mt][nt][r] = qq;         // reuse acc registers for q
                rsum[mt][r] += qq;
            }
        }
    }
    // reduce row partials across 16 lanes sharing a row, then across 4 waves via LDS
#pragma unroll
    for (int mt = 0; mt < 4; ++mt)
#pragma unroll
        for (int r = 0; r < 4; ++r) {
            float s = rsum[mt][r];
            s += __shfl_xor(s, 1, 64);
            s += __shfl_xor(s, 2, 64);
            s += __shfl_xor(s, 4, 64);
            s += __shfl_xor(s, 8, 64);
            if (l15 == 0) rs_lds[mt * 16 + q * 4 + r][w] = s;
        }
    __syncthreads();
    if (t < MT) {
        float s = rs_lds[t][0] + rs_lds[t][1] + rs_lds[t][2] + rs_lds[t][3];
        inv_lds[t] = __builtin_amdgcn_rcpf(s);
    }
    __syncthreads();

    // ---- store normalized q (coalesced: 16 consecutive floats per quad) ----
#pragma unroll
    for (int mt = 0; mt < 4; ++mt)
#pragma unroll
        for (int r = 0; r < 4; ++r) {
            int row = mt * 16 + q * 4 + r;
            float inv = inv_lds[row];
            float* orow = out + (long)(m0 + row) * NCL + w * 128;
#pragma unroll
            for (int nt = 0; nt < 8; ++nt)
                orow[nt * 16 + l15] = acc[mt][nt][r] * inv;
        }
}

extern "C" void kernel_launch(void* const* d_in, const int* in_sizes, int n_in,
                              void* d_out, int out_size, void* d_ws, size_t ws_size,
                              hipStream_t stream) {
    const float* x       = (const float*)d_in[0];
    const float* centers = (const float*)d_in[1];
    float* out           = (float*)d_out;

    unsigned short* cb = (unsigned short*)d_ws;                         // 512*512 bf16 = 512 KB
    float* c2          = (float*)((char*)d_ws + NCL * DDIM * sizeof(unsigned short)); // 2 KB

    prep_centers<<<NCL, 128, 0, stream>>>(centers, cb, c2);
    dec_soft_assign<<<NROWS / MT, 256, 0, stream>>>(x, cb, c2, out);
}

// Round 3
// 546.152 us; speedup vs baseline: 1.1465x; 1.1465x over previous
//
#include <hip/hip_runtime.h>

// DEC soft assignment: q = rownorm(1/(1 + ||x-c||^2)), ALPHA=1 so power term is identity.
// bf16 MFMA for x.c^T (error budget: dq ~ 2e-7 << 4e-5 threshold); fp32 x^2/c^2/normalize.
// R2: MT 64, 256thr, wave 64x128, BK=32, B via gload_lds + XOR-chunk swizzle. (214 us)
// R3: B direct from L2 -- REGRESSED (242): no reg headroom to pipeline, serial L2 latency.
// R4: raw-barrier counted-vmcnt pipeline -- REGRESSED (354): sched_barrier pinning + deep
//     prefetch spilled to scratch (FETCH/WRITE both inflated ~2x). Reverted.
// R5: occupancy attack. R2 was 2 blocks/CU because acc[4][8] = 128 AGPRs + 112 VGPRs ~ 240
//     unified regs -> 2 waves/SIMD. Now: 512-thread blocks, wave tile 64x64 -> acc 64 regs,
//     launch_bounds(512,4) -> 16 waves/CU (2 blocks). BK 32->64: 8 K-steps, half the
//     vmcnt-drain events. Same verified 2-barrier skeleton, swizzles generalized to 8-chunk.

typedef __attribute__((ext_vector_type(8))) short short8_t;
typedef __attribute__((ext_vector_type(4))) short short4_t;
typedef __attribute__((ext_vector_type(4))) float f32x4;

#define NROWS 131072
#define DDIM  512
#define NCL   512
#define BK    64
#define MT    64
#define APAD  72   // A row stride in shorts: 144B = rotate-by-4-banks/row, uniform b128 spread

__device__ __forceinline__ unsigned short f2bf(float f) {
    unsigned u = __float_as_uint(f);
    u += 0x7FFFu + ((u >> 16) & 1u);
    return (unsigned short)(u >> 16);
}

// ---- prep: convert centers to bf16, compute ||c_k||^2 in fp32 ----
__global__ __launch_bounds__(128) void prep_centers(
        const float* __restrict__ c, unsigned short* __restrict__ cb,
        float* __restrict__ c2) {
    const int k = blockIdx.x, t = threadIdx.x;
    float4 v = ((const float4*)(c + k * DDIM))[t];
    float ss = v.x * v.x + v.y * v.y + v.z * v.z + v.w * v.w;
    short4_t s;
    s.x = (short)f2bf(v.x); s.y = (short)f2bf(v.y);
    s.z = (short)f2bf(v.z); s.w = (short)f2bf(v.w);
    ((short4_t*)(cb + k * DDIM))[t] = s;
#pragma unroll
    for (int off = 32; off >= 1; off >>= 1) ss += __shfl_xor(ss, off, 64);
    __shared__ float red[2];
    if ((t & 63) == 0) red[t >> 6] = ss;
    __syncthreads();
    if (t == 0) c2[k] = red[0] + red[1];
}

// ---- main: 64 rows x 512 clusters per block, 512 threads = 8 waves (each 64x64) ----
__global__ __launch_bounds__(512, 4) void dec_soft_assign(
        const float* __restrict__ x, const unsigned short* __restrict__ cb,
        const float* __restrict__ c2g, float* __restrict__ out) {
    __shared__ __align__(16) unsigned short Alds[MT * APAD];   // 9.0 KB
    __shared__ __align__(16) unsigned short Blds[NCL * BK];    // 64 KB, XOR-chunk swizzled
    __shared__ float x2_lds[MT];
    __shared__ float rs_lds[MT][8];
    __shared__ float inv_lds[MT];

    const int t   = threadIdx.x;   // 0..511
    const int w   = t >> 6;        // wave 0..7
    const int l   = t & 63;
    const int q   = l >> 4;        // quad
    const int l15 = l & 15;
    const int m0  = blockIdx.x * MT;

    // A staging: thread t owns row ar, 8-elem k-chunk ac per step (of 64 k)
    const int ar  = t >> 3;        // 0..63
    const int ac  = t & 7;         // 0..7
    const float4* xp = (const float4*)(x + (long)(m0 + ar) * DDIM) + ac * 2;

    // B staging: 512 cols x 8 chunks(16B) = 4096 chunks; wave w, instr i, lane l
    // handles linear chunk cl = w*512 + i*64 + l. Physical slot (n,pc) holds global
    // chunk c = pc ^ (n&7). Since i -> i+1 advances n by 8, c is i-invariant:
    // source short offset = bgo0 + i*4096 + s*64.
    int bgo0;
    {
        int cl = w * 512 + l;
        int n  = cl >> 3;
        int pc = cl & 7;
        int c  = pc ^ (n & 7);
        bgo0   = n * DDIM + c * 8;
    }

    f32x4 acc[4][4];
#pragma unroll
    for (int mt = 0; mt < 4; ++mt)
#pragma unroll
        for (int nt = 0; nt < 4; ++nt)
            acc[mt][nt] = (f32x4){0.f, 0.f, 0.f, 0.f};

    float x2a = 0.f;
    float4 v0 = xp[0], v1 = xp[1];

    for (int s = 0; s < 8; ++s) {
        __syncthreads();                     // previous tile's LDS reads done
        // ---- stage A: fp32 -> bf16 (b128 write), accumulate ||x||^2 in fp32 ----
        x2a += v0.x * v0.x + v0.y * v0.y + v0.z * v0.z + v0.w * v0.w;
        x2a += v1.x * v1.x + v1.y * v1.y + v1.z * v1.z + v1.w * v1.w;
        short8_t a8;
        a8[0] = (short)f2bf(v0.x); a8[1] = (short)f2bf(v0.y);
        a8[2] = (short)f2bf(v0.z); a8[3] = (short)f2bf(v0.w);
        a8[4] = (short)f2bf(v1.x); a8[5] = (short)f2bf(v1.y);
        a8[6] = (short)f2bf(v1.z); a8[7] = (short)f2bf(v1.w);
        *(short8_t*)&Alds[ar * APAD + ac * 8] = a8;
        // ---- stage B: async 16B direct-to-LDS (lane-ordered dest, swizzled source) ----
#pragma unroll
        for (int i = 0; i < 8; ++i) {
            __builtin_amdgcn_global_load_lds(
                (const __attribute__((address_space(1))) void*)(cb + bgo0 + i * 4096 + s * BK),
                (__attribute__((address_space(3))) void*)&Blds[w * 4096 + i * 512],
                16, 0, 0);
        }
        __syncthreads();                     // staging visible (vmcnt drained by barrier)
        if (s < 7) { v0 = xp[(s + 1) * 16]; v1 = xp[(s + 1) * 16 + 1]; } // overlap MFMA

        // ---- MFMA phase: 4 (M) x 4 (N) tiles of 16x16, two K=32 sub-steps ----
#pragma unroll
        for (int kk = 0; kk < 2; ++kk) {
            short8_t afr[4], bfr[4];
#pragma unroll
            for (int mt = 0; mt < 4; ++mt)
                afr[mt] = *(const short8_t*)&Alds[(mt * 16 + l15) * APAD + kk * 32 + q * 8];
#pragma unroll
            for (int nt = 0; nt < 4; ++nt) {
                int n  = w * 64 + nt * 16 + l15;
                int pc = (kk * 4 + q) ^ (n & 7);
                bfr[nt] = *(const short8_t*)&Blds[n * BK + pc * 8];
            }
#pragma unroll
            for (int nt = 0; nt < 4; ++nt)
#pragma unroll
                for (int mt = 0; mt < 4; ++mt)
                    acc[mt][nt] = __builtin_amdgcn_mfma_f32_16x16x32_bf16(afr[mt], bfr[nt], acc[mt][nt], 0, 0, 0);
        }
    }

    // ---- x^2 per row: reduce the 8 staging lanes of each row ----
    x2a += __shfl_xor(x2a, 1, 64);
    x2a += __shfl_xor(x2a, 2, 64);
    x2a += __shfl_xor(x2a, 4, 64);
    if (ac == 0) x2_lds[ar] = x2a;
    __syncthreads();

    // ---- epilogue: dist2 -> clamp -> 1/(1+d), row sums ----
    float c2v[4];
#pragma unroll
    for (int nt = 0; nt < 4; ++nt)
        c2v[nt] = c2g[w * 64 + nt * 16 + l15];

    float rsum[4][4];
#pragma unroll
    for (int mt = 0; mt < 4; ++mt)
#pragma unroll
        for (int r = 0; r < 4; ++r) rsum[mt][r] = 0.f;

#pragma unroll
    for (int mt = 0; mt < 4; ++mt) {
#pragma unroll
        for (int r = 0; r < 4; ++r) {
            float xv = x2_lds[mt * 16 + q * 4 + r];
#pragma unroll
            for (int nt = 0; nt < 4; ++nt) {
                float d = xv + c2v[nt] - 2.0f * acc[mt][nt][r];
                d = fmaxf(d, 0.0f);
                float qq = __builtin_amdgcn_rcpf(1.0f + d);
                acc[mt][nt][r] = qq;         // reuse acc registers for q
                rsum[mt][r] += qq;
            }
        }
    }
    // reduce row partials across 16 lanes sharing a row, then across 8 waves via LDS
#pragma unroll
    for (int mt = 0; mt < 4; ++mt)
#pragma unroll
        for (int r = 0; r < 4; ++r) {
            float s = rsum[mt][r];
            s += __shfl_xor(s, 1, 64);
            s += __shfl_xor(s, 2, 64);
            s += __shfl_xor(s, 4, 64);
            s += __shfl_xor(s, 8, 64);
            if (l15 == 0) rs_lds[mt * 16 + q * 4 + r][w] = s;
        }
    __syncthreads();
    if (t < MT) {
        float s = rs_lds[t][0] + rs_lds[t][1] + rs_lds[t][2] + rs_lds[t][3]
                + rs_lds[t][4] + rs_lds[t][5] + rs_lds[t][6] + rs_lds[t][7];
        inv_lds[t] = __builtin_amdgcn_rcpf(s);
    }
    __syncthreads();

    // ---- store normalized q (coalesced: 16 consecutive floats per quad) ----
#pragma unroll
    for (int mt = 0; mt < 4; ++mt)
#pragma unroll
        for (int r = 0; r < 4; ++r) {
            int row = mt * 16 + q * 4 + r;
            float inv = inv_lds[row];
            float* orow = out + (long)(m0 + row) * NCL + w * 64;
#pragma unroll
            for (int nt = 0; nt < 4; ++nt)
                orow[nt * 16 + l15] = acc[mt][nt][r] * inv;
        }
}

extern "C" void kernel_launch(void* const* d_in, const int* in_sizes, int n_in,
                              void* d_out, int out_size, void* d_ws, size_t ws_size,
                              hipStream_t stream) {
    const float* x       = (const float*)d_in[0];
    const float* centers = (const float*)d_in[1];
    float* out           = (float*)d_out;

    unsigned short* cb = (unsigned short*)d_ws;                         // 512*512 bf16 = 512 KB
    float* c2          = (float*)((char*)d_ws + NCL * DDIM * sizeof(unsigned short)); // 2 KB

    prep_centers<<<NCL, 128, 0, stream>>>(centers, cb, c2);
    dec_soft_assign<<<NROWS / MT, 512, 0, stream>>>(x, cb, c2, out);
}